// Round 6
// baseline (170.779 us; speedup 1.0000x reference)
//
#include <hip/hip_runtime.h>

// MPS tensor-train classifier, B=16384, D=784, BOND=5, OUT=10.
//
// res[b] = carry0(x0) . (prod_{m=0..781} M_m(x[m+1])) . vlast(x783)
// Pair p (sites 2p+1, 2p+2):  C_p = P0 + xa*P1 + xb*P2 + xa*xb*P3
// (P0..P3 prepacked, 25 floats each, 100 floats/pair; N = A1-A0).
// Pairs >= BWD_P0 stored TRANSPOSED for the bwd row-vector chain.
//
// Round-6 vs round-5 (63 us kernel, VALUBusy 37%, occupancy capped at 16
// waves/CU by the 1024-thread single-block-per-CU structure):
//  * CHAIN SPLIT ACROSS 2 BLOCKS: front block = site0 + pairs 0..194,
//    back block = pairs 195..389 + site 781. 512 blocks -> 2 blocks/CU ->
//    32 waves/CU (8/SIMD): 2x latency-hiding, per-wave work halves.
//    Halves exchanged through d_out (f -> cols 0..4, g -> cols 5..9);
//    tiny finalize kernel computes res*fc_w + fc_b.
//  * PLAIN SCALAR fmaf everywhere: v2f/VOP3P experiment cost ~2.7x VALU
//    (mov-staging of SGPR pairs). v_fma_f32 takes 1 SGPR source directly:
//    buildC element = mul(s)+fma(s)+fma(s)+add(s), zero movs.
//  * matbuf [8][25][64] = 51.2 KB (2-phase combine) so 2 blocks/CU fit LDS.
//
// Per block: 16 waves, lane = batch row (64 rows/block).
//   front: wave 0 = fwd vec (site0 + pairs 0..14), waves 1..15 = 12-pair
//          matrix segments (p0 = 15+12(w-1)); combine ascending.
//   back:  waves 0..14 = 12-pair matrix segments (p0 = 195+12w), wave 15 =
//          bwd vec (site 781 + pairs 389..375 desc, transposed pk);
//          combine descending (column form).

constexpr int Bn     = 16384;
constexpr int Dn     = 784;
constexpr int NOUT   = 10;
constexpr int NPAIR  = 390;   // pairs cover sites 1..780
constexpr int PKP    = 100;   // floats per pair block (400 B): mat q at q*25
constexpr int BWD_P0 = 375;   // bwd vec pairs 375..389 (stored transposed)

// ---- prepack: pair blocks, plain 25-float row-major mats ----
// cores_mid element (m,l,i,k) at (m*5+l)*10 + i*5 + k
__global__ void prepack_pairs(const float* __restrict__ cm, float* __restrict__ pk)
{
    int idx = blockIdx.x * 256 + threadIdx.x;
    if (idx >= NPAIR * 100) return;
    int p = idx / 100, rest = idx - p * 100;
    int q = rest / 25, e = rest - q * 25;
    int l = e / 5, r = e - l * 5;
    int m1 = 2 * p + 1, m2 = 2 * p + 2;
    const float* L = cm + (size_t)(m1 * 5 + l) * 10;
    float acc = 0.f;
#pragma unroll
    for (int k = 0; k < 5; ++k) {
        float Lk = (q & 1) ? (L[5 + k] - L[k]) : L[k];
        const float* R = cm + (size_t)(m2 * 5 + k) * 10;
        float Rk = (q & 2) ? (R[5 + r] - R[r]) : R[r];
        acc = fmaf(Lk, Rk, acc);
    }
    int wl = l, wr = r;
    if (p >= BWD_P0) { wl = r; wr = l; }   // store C^T for the bwd wave
    pk[(size_t)p * PKP + q * 25 + wl * 5 + wr] = acc;
}

// C = P0 + xa*P1 + xb*P2 + xa*xb*P3.  Per element: v_mul(s) + 2x v_fma(s)
// + v_add(s) — exactly one SGPR source per instruction, no v_mov staging.
__device__ __forceinline__ void buildC(const float* __restrict__ s,
                                       float xa, float xb, float C[25]) {
    const float xab = xa * xb;
#pragma unroll
    for (int k = 0; k < 25; ++k) {
        float t = xab * s[75 + k];
        t = fmaf(xb, s[50 + k], t);
        t = fmaf(xa, s[25 + k], t);
        C[k] = t + s[k];
    }
}

// c <- c @ C   (row 5-vector)
__device__ __forceinline__ void vstep(float c[5], const float C[25]) {
    float t[5];
#pragma unroll
    for (int r = 0; r < 5; ++r) t[r] = c[0] * C[r];
#pragma unroll
    for (int l = 1; l < 5; ++l)
#pragma unroll
        for (int r = 0; r < 5; ++r) t[r] = fmaf(c[l], C[l * 5 + r], t[r]);
#pragma unroll
    for (int r = 0; r < 5; ++r) c[r] = t[r];
}

// M <- M @ C   (in-place, row by row)
__device__ __forceinline__ void mstep(float M[25], const float C[25]) {
#pragma unroll
    for (int i = 0; i < 5; ++i) {
        float t[5];
#pragma unroll
        for (int r = 0; r < 5; ++r) t[r] = M[i * 5] * C[r];
#pragma unroll
        for (int l = 1; l < 5; ++l)
#pragma unroll
            for (int r = 0; r < 5; ++r) t[r] = fmaf(M[i * 5 + l], C[l * 5 + r], t[r]);
#pragma unroll
        for (int r = 0; r < 5; ++r) M[i * 5 + r] = t[r];
    }
}

__global__ __launch_bounds__(1024, 8)
void mps_half_kernel(const float* __restrict__ x,          // [B, D]
                     const float* __restrict__ core_first, // [2,5]
                     const float* __restrict__ cores_mid,  // [782,5,2,5]
                     const float* __restrict__ core_last,  // [5,2]
                     const float* __restrict__ pk,         // [390][100]
                     float* __restrict__ out)              // [B,10]: f|g
{
    __shared__ float matbuf[8][25][64];   // 51.2 KB, 2-phase

    const int lane = threadIdx.x & 63;
    const int wseg = __builtin_amdgcn_readfirstlane(threadIdx.x >> 6);
    const int half = blockIdx.x & 1;           // 0 = front, 1 = back
    const int row  = (blockIdx.x >> 1) * 64 + lane;
    const float*  __restrict__ xr  = x + (size_t)row * Dn;
    const float2* __restrict__ xr2 = (const float2*)xr;   // 392 entries

    const bool isVec = (half == 0) ? (wseg == 0) : (wseg == 15);

    float M[25];   // matrix waves: running product
    float cl[5];   // vec waves: running vector
    float C[25];

    if (!isVec) {
        const int p0 = (half == 0) ? (15 + 12 * (wseg - 1)) : (195 + 12 * wseg);
        const float* __restrict__ s = pk + (size_t)p0 * PKP;
#pragma unroll
        for (int k = 0; k < 25; ++k) M[k] = (k % 6 == 0) ? 1.0f : 0.0f;
#pragma unroll 1
        for (int i = 0; i < 12; ++i) {
            const float2 xv = xr2[p0 + i + 1];   // {x[2p+2], x[2p+3]}
            buildC(s, xv.x, xv.y, C);
            mstep(M, C);
            s += PKP;
        }
    } else if (half == 0) {
        // ---- fwd vec: carry0, site 0 (single), pairs 0..14 ----
        const float2 x01 = xr2[0];
        float cn[5];
#pragma unroll
        for (int r = 0; r < 5; ++r)
            cl[r] = fmaf(x01.x, core_first[5 + r] - core_first[r], core_first[r]);
        const float* cm0 = cores_mid;            // site m=0
#pragma unroll
        for (int r = 0; r < 5; ++r) {
            float a = 0.f;
#pragma unroll
            for (int l = 0; l < 5; ++l) {
                float mm = fmaf(x01.y, cm0[l * 10 + 5 + r] - cm0[l * 10 + r],
                                cm0[l * 10 + r]);
                a = fmaf(cl[l], mm, a);
            }
            cn[r] = a;
        }
#pragma unroll
        for (int r = 0; r < 5; ++r) cl[r] = cn[r];
        const float* __restrict__ s = pk;
#pragma unroll 1
        for (int p = 0; p < 15; ++p) {
            const float2 xv = xr2[p + 1];
            buildC(s, xv.x, xv.y, C);
            vstep(cl, C);
            s += PKP;
        }
    } else {
        // ---- bwd vec: vlast, site 781 (single), pairs 389..375 desc ----
        const float2 xz = xr2[391];              // {x[782], x[783]}
        float vl[5], vn[5];
#pragma unroll
        for (int l = 0; l < 5; ++l)
            vl[l] = fmaf(xz.y, core_last[2 * l + 1] - core_last[2 * l],
                         core_last[2 * l]);
        const float* cmL = cores_mid + (size_t)781 * 50;   // site m=781
#pragma unroll
        for (int l = 0; l < 5; ++l) {
            float a = 0.f;
#pragma unroll
            for (int r = 0; r < 5; ++r) {
                float mm = fmaf(xz.x, cmL[l * 10 + 5 + r] - cmL[l * 10 + r],
                                cmL[l * 10 + r]);
                a = fmaf(mm, vl[r], a);
            }
            vn[l] = a;
        }
#pragma unroll
        for (int l = 0; l < 5; ++l) cl[l] = vn[l];
        const float* __restrict__ s = pk + (size_t)(NPAIR - 1) * PKP;
#pragma unroll 1
        for (int p = NPAIR - 1; p >= BWD_P0; --p) {
            const float2 xv = xr2[p + 1];
            buildC(s, xv.x, xv.y, C);            // transposed pk
            vstep(cl, C);                        // row-form of column chain
            s -= PKP;
        }
    }

    // ---- phase 1 write: front waves 1..8 (P1..P8), back waves 8..14 (Q8..Q14)
    if (!isVec && ((half == 0 && wseg <= 8) || (half == 1 && wseg >= 8))) {
        const int slot = (half == 0) ? (wseg - 1) : (wseg - 8);
#pragma unroll
        for (int k = 0; k < 25; ++k) matbuf[slot][k][lane] = M[k];
    }
    __syncthreads();   // b1

    if (isVec) {
        if (half == 0) {
            // f = cl @ P1 @ ... @ P8 (ascending slots)
#pragma unroll 1
            for (int s2 = 0; s2 < 8; ++s2) {
                float t[5];
#pragma unroll
                for (int r = 0; r < 5; ++r) t[r] = cl[0] * matbuf[s2][r][lane];
#pragma unroll
                for (int l = 1; l < 5; ++l)
#pragma unroll
                    for (int r = 0; r < 5; ++r)
                        t[r] = fmaf(cl[l], matbuf[s2][l * 5 + r][lane], t[r]);
#pragma unroll
                for (int r = 0; r < 5; ++r) cl[r] = t[r];
            }
        } else {
            // h = Q14 @ (... @ (Q8 @ h)) : descending slots 6..0, column form
#pragma unroll 1
            for (int s2 = 6; s2 >= 0; --s2) {
                float t[5];
#pragma unroll
                for (int l = 0; l < 5; ++l) {
                    float a = matbuf[s2][l * 5][lane] * cl[0];
#pragma unroll
                    for (int r = 1; r < 5; ++r)
                        a = fmaf(matbuf[s2][l * 5 + r][lane], cl[r], a);
                    t[l] = a;
                }
#pragma unroll
                for (int l = 0; l < 5; ++l) cl[l] = t[l];
            }
        }
    }
    __syncthreads();   // b2

    // ---- phase 2 write: front waves 9..15 (P9..P15), back waves 0..7 (Q0..Q7)
    if (!isVec && ((half == 0 && wseg >= 9) || (half == 1 && wseg <= 7))) {
        const int slot = (half == 0) ? (wseg - 9) : wseg;
#pragma unroll
        for (int k = 0; k < 25; ++k) matbuf[slot][k][lane] = M[k];
    }
    __syncthreads();   // b3

    if (isVec) {
        float* orow = out + (size_t)row * NOUT;
        if (half == 0) {
#pragma unroll 1
            for (int s2 = 0; s2 < 7; ++s2) {     // P9..P15 ascending
                float t[5];
#pragma unroll
                for (int r = 0; r < 5; ++r) t[r] = cl[0] * matbuf[s2][r][lane];
#pragma unroll
                for (int l = 1; l < 5; ++l)
#pragma unroll
                    for (int r = 0; r < 5; ++r)
                        t[r] = fmaf(cl[l], matbuf[s2][l * 5 + r][lane], t[r]);
#pragma unroll
                for (int r = 0; r < 5; ++r) cl[r] = t[r];
            }
#pragma unroll
            for (int i = 0; i < 5; ++i) orow[i] = cl[i];        // f
        } else {
#pragma unroll 1
            for (int s2 = 7; s2 >= 0; --s2) {    // Q7..Q0 descending
                float t[5];
#pragma unroll
                for (int l = 0; l < 5; ++l) {
                    float a = matbuf[s2][l * 5][lane] * cl[0];
#pragma unroll
                    for (int r = 1; r < 5; ++r)
                        a = fmaf(matbuf[s2][l * 5 + r][lane], cl[r], a);
                    t[l] = a;
                }
#pragma unroll
                for (int l = 0; l < 5; ++l) cl[l] = t[l];
            }
#pragma unroll
            for (int i = 0; i < 5; ++i) orow[5 + i] = cl[i];    // g
        }
    }
}

// out[row] currently holds [f0..f4, g0..g4]; replace with res*fc_w + fc_b
__global__ __launch_bounds__(256)
void finalize_kernel(const float* __restrict__ fc_w, const float* __restrict__ fc_b,
                     float* __restrict__ out)
{
    const int row = blockIdx.x * 256 + threadIdx.x;   // 16384 threads
    float* o = out + (size_t)row * NOUT;
    float f[5], g[5];
#pragma unroll
    for (int i = 0; i < 5; ++i) { f[i] = o[i]; g[i] = o[5 + i]; }
    float res = f[0] * g[0];
#pragma unroll
    for (int i = 1; i < 5; ++i) res = fmaf(f[i], g[i], res);
#pragma unroll
    for (int k = 0; k < NOUT; ++k) o[k] = fmaf(res, fc_w[k], fc_b[k]);
}

extern "C" void kernel_launch(void* const* d_in, const int* in_sizes, int n_in,
                              void* d_out, int out_size, void* d_ws, size_t ws_size,
                              hipStream_t stream) {
    const float* x          = (const float*)d_in[0];
    const float* core_first = (const float*)d_in[1];
    const float* cores_mid  = (const float*)d_in[2];
    const float* core_last  = (const float*)d_in[3];
    const float* fc_w       = (const float*)d_in[4];
    const float* fc_b       = (const float*)d_in[5];
    float* out              = (float*)d_out;
    float* pk               = (float*)d_ws;   // 390*100*4 = 156,000 B

    hipLaunchKernelGGL(prepack_pairs, dim3((NPAIR * 100 + 255) / 256), dim3(256),
                       0, stream, cores_mid, pk);
    hipLaunchKernelGGL(mps_half_kernel, dim3(Bn / 64 * 2), dim3(1024), 0, stream,
                       x, core_first, cores_mid, core_last, pk, out);
    hipLaunchKernelGGL(finalize_kernel, dim3(Bn / 256), dim3(256), 0, stream,
                       fc_w, fc_b, out);
}

// Round 7
// 141.004 us; speedup vs baseline: 1.2112x; 1.2112x over previous
//
#include <hip/hip_runtime.h>

// MPS tensor-train classifier, B=16384, D=784, BOND=5, OUT=10.
//
// res[b] = carry0(x0) . (prod_{m=0..781} M_m(x[m+1])) . vlast(x783)
// Pair p (sites 2p+1, 2p+2):  C_p = P0 + xa*P1 + xb*P2 + xa*xb*P3
// (P0..P3 prepacked, 25 floats each, 100 floats/pair; N = A1-A0).
// Pairs >= BWD_P0 stored TRANSPOSED for the bwd row-vector chain.
//
// Round-7 vs round-6: ONLY __launch_bounds__(1024, 8) -> (1024, 4).
// Round 6's min-8-waves/EU hint made the allocator squeeze to 32 VGPRs and
// spill M[25]+C[25] to scratch (WRITE_SIZE 123 MB, kernel 87 us). The same
// math compiles to 52 VGPRs under the (1024,4) cap (round 5, no spill), and
// 52 <= 64 = the true VGPR budget for 8 waves/EU — so with LDS at 51.2 KB
// the HARDWARE already schedules 2 blocks/CU (32 waves/CU) from actual
// resource use; no allocator pressure needed.
//
// Per block: 16 waves, lane = batch row (64 rows/block).
//   front (even blockIdx): wave 0 = fwd vec (site0 + pairs 0..14),
//     waves 1..15 = 12-pair matrix segments (p0 = 15+12(w-1)).
//   back (odd blockIdx):  waves 0..14 = 12-pair matrix segments
//     (p0 = 195+12w), wave 15 = bwd vec (site 781 + pairs 389..375 desc).
// Halves exchanged through d_out (f -> cols 0..4, g -> cols 5..9);
// finalize kernel computes res*fc_w + fc_b.

constexpr int Bn     = 16384;
constexpr int Dn     = 784;
constexpr int NOUT   = 10;
constexpr int NPAIR  = 390;   // pairs cover sites 1..780
constexpr int PKP    = 100;   // floats per pair block (400 B): mat q at q*25
constexpr int BWD_P0 = 375;   // bwd vec pairs 375..389 (stored transposed)

// ---- prepack: pair blocks, plain 25-float row-major mats ----
// cores_mid element (m,l,i,k) at (m*5+l)*10 + i*5 + k
__global__ void prepack_pairs(const float* __restrict__ cm, float* __restrict__ pk)
{
    int idx = blockIdx.x * 256 + threadIdx.x;
    if (idx >= NPAIR * 100) return;
    int p = idx / 100, rest = idx - p * 100;
    int q = rest / 25, e = rest - q * 25;
    int l = e / 5, r = e - l * 5;
    int m1 = 2 * p + 1, m2 = 2 * p + 2;
    const float* L = cm + (size_t)(m1 * 5 + l) * 10;
    float acc = 0.f;
#pragma unroll
    for (int k = 0; k < 5; ++k) {
        float Lk = (q & 1) ? (L[5 + k] - L[k]) : L[k];
        const float* R = cm + (size_t)(m2 * 5 + k) * 10;
        float Rk = (q & 2) ? (R[5 + r] - R[r]) : R[r];
        acc = fmaf(Lk, Rk, acc);
    }
    int wl = l, wr = r;
    if (p >= BWD_P0) { wl = r; wr = l; }   // store C^T for the bwd wave
    pk[(size_t)p * PKP + q * 25 + wl * 5 + wr] = acc;
}

// C = P0 + xa*P1 + xb*P2 + xa*xb*P3.  Per element: v_mul(s) + 2x v_fma(s)
// + v_add(s) — exactly one SGPR source per instruction, no v_mov staging.
__device__ __forceinline__ void buildC(const float* __restrict__ s,
                                       float xa, float xb, float C[25]) {
    const float xab = xa * xb;
#pragma unroll
    for (int k = 0; k < 25; ++k) {
        float t = xab * s[75 + k];
        t = fmaf(xb, s[50 + k], t);
        t = fmaf(xa, s[25 + k], t);
        C[k] = t + s[k];
    }
}

// c <- c @ C   (row 5-vector)
__device__ __forceinline__ void vstep(float c[5], const float C[25]) {
    float t[5];
#pragma unroll
    for (int r = 0; r < 5; ++r) t[r] = c[0] * C[r];
#pragma unroll
    for (int l = 1; l < 5; ++l)
#pragma unroll
        for (int r = 0; r < 5; ++r) t[r] = fmaf(c[l], C[l * 5 + r], t[r]);
#pragma unroll
    for (int r = 0; r < 5; ++r) c[r] = t[r];
}

// M <- M @ C   (in-place, row by row)
__device__ __forceinline__ void mstep(float M[25], const float C[25]) {
#pragma unroll
    for (int i = 0; i < 5; ++i) {
        float t[5];
#pragma unroll
        for (int r = 0; r < 5; ++r) t[r] = M[i * 5] * C[r];
#pragma unroll
        for (int l = 1; l < 5; ++l)
#pragma unroll
            for (int r = 0; r < 5; ++r) t[r] = fmaf(M[i * 5 + l], C[l * 5 + r], t[r]);
#pragma unroll
        for (int r = 0; r < 5; ++r) M[i * 5 + r] = t[r];
    }
}

__global__ __launch_bounds__(1024, 4)
void mps_half_kernel(const float* __restrict__ x,          // [B, D]
                     const float* __restrict__ core_first, // [2,5]
                     const float* __restrict__ cores_mid,  // [782,5,2,5]
                     const float* __restrict__ core_last,  // [5,2]
                     const float* __restrict__ pk,         // [390][100]
                     float* __restrict__ out)              // [B,10]: f|g
{
    __shared__ float matbuf[8][25][64];   // 51.2 KB: 2 blocks/CU fit 160 KB

    const int lane = threadIdx.x & 63;
    const int wseg = __builtin_amdgcn_readfirstlane(threadIdx.x >> 6);
    const int half = blockIdx.x & 1;           // 0 = front, 1 = back
    const int row  = (blockIdx.x >> 1) * 64 + lane;
    const float*  __restrict__ xr  = x + (size_t)row * Dn;
    const float2* __restrict__ xr2 = (const float2*)xr;   // 392 entries

    const bool isVec = (half == 0) ? (wseg == 0) : (wseg == 15);

    float M[25];   // matrix waves: running product
    float cl[5];   // vec waves: running vector
    float C[25];

    if (!isVec) {
        const int p0 = (half == 0) ? (15 + 12 * (wseg - 1)) : (195 + 12 * wseg);
        const float* __restrict__ s = pk + (size_t)p0 * PKP;
#pragma unroll
        for (int k = 0; k < 25; ++k) M[k] = (k % 6 == 0) ? 1.0f : 0.0f;
#pragma unroll 1
        for (int i = 0; i < 12; ++i) {
            const float2 xv = xr2[p0 + i + 1];   // {x[2p+2], x[2p+3]}
            buildC(s, xv.x, xv.y, C);
            mstep(M, C);
            s += PKP;
        }
    } else if (half == 0) {
        // ---- fwd vec: carry0, site 0 (single), pairs 0..14 ----
        const float2 x01 = xr2[0];
        float cn[5];
#pragma unroll
        for (int r = 0; r < 5; ++r)
            cl[r] = fmaf(x01.x, core_first[5 + r] - core_first[r], core_first[r]);
        const float* cm0 = cores_mid;            // site m=0
#pragma unroll
        for (int r = 0; r < 5; ++r) {
            float a = 0.f;
#pragma unroll
            for (int l = 0; l < 5; ++l) {
                float mm = fmaf(x01.y, cm0[l * 10 + 5 + r] - cm0[l * 10 + r],
                                cm0[l * 10 + r]);
                a = fmaf(cl[l], mm, a);
            }
            cn[r] = a;
        }
#pragma unroll
        for (int r = 0; r < 5; ++r) cl[r] = cn[r];
        const float* __restrict__ s = pk;
#pragma unroll 1
        for (int p = 0; p < 15; ++p) {
            const float2 xv = xr2[p + 1];
            buildC(s, xv.x, xv.y, C);
            vstep(cl, C);
            s += PKP;
        }
    } else {
        // ---- bwd vec: vlast, site 781 (single), pairs 389..375 desc ----
        const float2 xz = xr2[391];              // {x[782], x[783]}
        float vl[5], vn[5];
#pragma unroll
        for (int l = 0; l < 5; ++l)
            vl[l] = fmaf(xz.y, core_last[2 * l + 1] - core_last[2 * l],
                         core_last[2 * l]);
        const float* cmL = cores_mid + (size_t)781 * 50;   // site m=781
#pragma unroll
        for (int l = 0; l < 5; ++l) {
            float a = 0.f;
#pragma unroll
            for (int r = 0; r < 5; ++r) {
                float mm = fmaf(xz.x, cmL[l * 10 + 5 + r] - cmL[l * 10 + r],
                                cmL[l * 10 + r]);
                a = fmaf(mm, vl[r], a);
            }
            vn[l] = a;
        }
#pragma unroll
        for (int l = 0; l < 5; ++l) cl[l] = vn[l];
        const float* __restrict__ s = pk + (size_t)(NPAIR - 1) * PKP;
#pragma unroll 1
        for (int p = NPAIR - 1; p >= BWD_P0; --p) {
            const float2 xv = xr2[p + 1];
            buildC(s, xv.x, xv.y, C);            // transposed pk
            vstep(cl, C);                        // row-form of column chain
            s -= PKP;
        }
    }

    // ---- phase 1 write: front waves 1..8 (P1..P8), back waves 8..14 (Q8..Q14)
    if (!isVec && ((half == 0 && wseg <= 8) || (half == 1 && wseg >= 8))) {
        const int slot = (half == 0) ? (wseg - 1) : (wseg - 8);
#pragma unroll
        for (int k = 0; k < 25; ++k) matbuf[slot][k][lane] = M[k];
    }
    __syncthreads();   // b1

    if (isVec) {
        if (half == 0) {
            // f = cl @ P1 @ ... @ P8 (ascending slots)
#pragma unroll 1
            for (int s2 = 0; s2 < 8; ++s2) {
                float t[5];
#pragma unroll
                for (int r = 0; r < 5; ++r) t[r] = cl[0] * matbuf[s2][r][lane];
#pragma unroll
                for (int l = 1; l < 5; ++l)
#pragma unroll
                    for (int r = 0; r < 5; ++r)
                        t[r] = fmaf(cl[l], matbuf[s2][l * 5 + r][lane], t[r]);
#pragma unroll
                for (int r = 0; r < 5; ++r) cl[r] = t[r];
            }
        } else {
            // h = Q14 @ (... @ (Q8 @ h)) : descending slots 6..0, column form
#pragma unroll 1
            for (int s2 = 6; s2 >= 0; --s2) {
                float t[5];
#pragma unroll
                for (int l = 0; l < 5; ++l) {
                    float a = matbuf[s2][l * 5][lane] * cl[0];
#pragma unroll
                    for (int r = 1; r < 5; ++r)
                        a = fmaf(matbuf[s2][l * 5 + r][lane], cl[r], a);
                    t[l] = a;
                }
#pragma unroll
                for (int l = 0; l < 5; ++l) cl[l] = t[l];
            }
        }
    }
    __syncthreads();   // b2

    // ---- phase 2 write: front waves 9..15 (P9..P15), back waves 0..7 (Q0..Q7)
    if (!isVec && ((half == 0 && wseg >= 9) || (half == 1 && wseg <= 7))) {
        const int slot = (half == 0) ? (wseg - 9) : wseg;
#pragma unroll
        for (int k = 0; k < 25; ++k) matbuf[slot][k][lane] = M[k];
    }
    __syncthreads();   // b3

    if (isVec) {
        float* orow = out + (size_t)row * NOUT;
        if (half == 0) {
#pragma unroll 1
            for (int s2 = 0; s2 < 7; ++s2) {     // P9..P15 ascending
                float t[5];
#pragma unroll
                for (int r = 0; r < 5; ++r) t[r] = cl[0] * matbuf[s2][r][lane];
#pragma unroll
                for (int l = 1; l < 5; ++l)
#pragma unroll
                    for (int r = 0; r < 5; ++r)
                        t[r] = fmaf(cl[l], matbuf[s2][l * 5 + r][lane], t[r]);
#pragma unroll
                for (int r = 0; r < 5; ++r) cl[r] = t[r];
            }
#pragma unroll
            for (int i = 0; i < 5; ++i) orow[i] = cl[i];        // f
        } else {
#pragma unroll 1
            for (int s2 = 7; s2 >= 0; --s2) {    // Q7..Q0 descending
                float t[5];
#pragma unroll
                for (int l = 0; l < 5; ++l) {
                    float a = matbuf[s2][l * 5][lane] * cl[0];
#pragma unroll
                    for (int r = 1; r < 5; ++r)
                        a = fmaf(matbuf[s2][l * 5 + r][lane], cl[r], a);
                    t[l] = a;
                }
#pragma unroll
                for (int l = 0; l < 5; ++l) cl[l] = t[l];
            }
#pragma unroll
            for (int i = 0; i < 5; ++i) orow[5 + i] = cl[i];    // g
        }
    }
}

// out[row] currently holds [f0..f4, g0..g4]; replace with res*fc_w + fc_b
__global__ __launch_bounds__(256)
void finalize_kernel(const float* __restrict__ fc_w, const float* __restrict__ fc_b,
                     float* __restrict__ out)
{
    const int row = blockIdx.x * 256 + threadIdx.x;   // 16384 threads
    float* o = out + (size_t)row * NOUT;
    float f[5], g[5];
#pragma unroll
    for (int i = 0; i < 5; ++i) { f[i] = o[i]; g[i] = o[5 + i]; }
    float res = f[0] * g[0];
#pragma unroll
    for (int i = 1; i < 5; ++i) res = fmaf(f[i], g[i], res);
#pragma unroll
    for (int k = 0; k < NOUT; ++k) o[k] = fmaf(res, fc_w[k], fc_b[k]);
}

extern "C" void kernel_launch(void* const* d_in, const int* in_sizes, int n_in,
                              void* d_out, int out_size, void* d_ws, size_t ws_size,
                              hipStream_t stream) {
    const float* x          = (const float*)d_in[0];
    const float* core_first = (const float*)d_in[1];
    const float* cores_mid  = (const float*)d_in[2];
    const float* core_last  = (const float*)d_in[3];
    const float* fc_w       = (const float*)d_in[4];
    const float* fc_b       = (const float*)d_in[5];
    float* out              = (float*)d_out;
    float* pk               = (float*)d_ws;   // 390*100*4 = 156,000 B

    hipLaunchKernelGGL(prepack_pairs, dim3((NPAIR * 100 + 255) / 256), dim3(256),
                       0, stream, cores_mid, pk);
    hipLaunchKernelGGL(mps_half_kernel, dim3(Bn / 64 * 2), dim3(1024), 0, stream,
                       x, core_first, cores_mid, core_last, pk, out);
    hipLaunchKernelGGL(finalize_kernel, dim3(Bn / 256), dim3(256), 0, stream,
                       fc_w, fc_b, out);
}